// Round 1
// baseline (607.882 us; speedup 1.0000x reference)
//
#include <hip/hip_runtime.h>

typedef unsigned short u16;
typedef __attribute__((ext_vector_type(8))) unsigned short u16x8;
typedef __bf16 bf16x8 __attribute__((ext_vector_type(8)));
typedef float f32x4 __attribute__((ext_vector_type(4)));

__device__ __forceinline__ u16 f2b(float f) {
    unsigned u = __float_as_uint(f);
    u += 0x7fffu + ((u >> 16) & 1u);   // RNE bf16 (finite values only)
    return (u16)(u >> 16);
}
__device__ __forceinline__ float b2f(u16 h) {
    return __uint_as_float(((unsigned)h) << 16);
}

__device__ __forceinline__ void async_copy16(const void* g, void* l) {
    __builtin_amdgcn_global_load_lds(
        (const __attribute__((address_space(1))) unsigned int*)g,
        (__attribute__((address_space(3))) unsigned int*)l,
        16, 0, 0);
}

// ---------------- cast f32 -> bf16, 8 elems/thread ----------------
__global__ __launch_bounds__(256) void cast_kernel(const float* __restrict__ in,
                                                   u16* __restrict__ out, long n) {
    long i0 = ((long)blockIdx.x * 256 + threadIdx.x) * 8;
    long stride = (long)gridDim.x * 256 * 8;
    for (long i = i0; i < n; i += stride) {
        float4 a = *(const float4*)(in + i);
        float4 b = *(const float4*)(in + i + 4);
        u16x8 o;
        o[0] = f2b(a.x); o[1] = f2b(a.y); o[2] = f2b(a.z); o[3] = f2b(a.w);
        o[4] = f2b(b.x); o[5] = f2b(b.y); o[6] = f2b(b.z); o[7] = f2b(b.w);
        *(u16x8*)(out + i) = o;
    }
}

// ---------------- bf16 transpose (per batch) ----------------
__global__ __launch_bounds__(256) void transpose_kernel(const u16* __restrict__ in,
                                                        u16* __restrict__ out,
                                                        int rows, int cols) {
    __shared__ u16 tile[32][33];
    long base = (long)blockIdx.z * rows * cols;
    const u16* I = in + base;
    u16* O = out + base;
    int r0 = blockIdx.y * 32, c0 = blockIdx.x * 32;
    int tx = threadIdx.x, ty = threadIdx.y;
    #pragma unroll
    for (int j = ty; j < 32; j += 8)
        tile[j][tx] = I[(long)(r0 + j) * cols + c0 + tx];
    __syncthreads();
    #pragma unroll
    for (int j = ty; j < 32; j += 8)
        O[(long)(c0 + j) * rows + r0 + tx] = tile[tx][j];
}

// ---------------- row softmax over causal prefix, in place ----------------
// Sc layout: [B*S][S] bf16. Row q (within batch) valid cols [0, q]; writes
// P = softmax over that prefix and zeros cols (q, roundup128(q+1)).
__global__ __launch_bounds__(256) void softmax_kernel(u16* __restrict__ Sc) {
    const int SS = 2048;
    long row = blockIdx.x;
    int q = (int)(row & (SS - 1));
    int L = q + 1;
    int Klim = ((q >> 7) + 1) << 7;       // roundup(L,128)
    u16* p = Sc + row * SS;
    int tid = threadIdx.x;

    float m = -1e30f;
    for (int i = tid; i < L; i += 256) m = fmaxf(m, b2f(p[i]));
    #pragma unroll
    for (int o = 32; o > 0; o >>= 1) m = fmaxf(m, __shfl_xor(m, o));
    __shared__ float redm[4];
    if ((tid & 63) == 0) redm[tid >> 6] = m;
    __syncthreads();
    m = fmaxf(fmaxf(redm[0], redm[1]), fmaxf(redm[2], redm[3]));

    float s = 0.f;
    for (int i = tid; i < L; i += 256) s += __expf(b2f(p[i]) - m);
    #pragma unroll
    for (int o = 32; o > 0; o >>= 1) s += __shfl_xor(s, o);
    __shared__ float reds[4];
    if ((tid & 63) == 0) reds[tid >> 6] = s;
    __syncthreads();
    s = reds[0] + reds[1] + reds[2] + reds[3];
    float inv = 1.f / s;

    for (int i = tid; i < Klim; i += 256) {
        float v = (i < L) ? __expf(b2f(p[i]) - m) * inv : 0.f;
        p[i] = f2b(v);
    }
}

// ---------------- bf16 BT-GEMM, m97 structure ----------------
// C[m,n] = (sum_k A[m,k]*B[n,k]) * scale (+ bias[n]); A:[M,K] B:[N,K] row-major.
// 128x128 tile, BK=32, 4 waves, 16x16x32 MFMA, global_load_lds width 16.
// CSKIP: skip blocks with bn > bm (causal upper triangle).
// KLIM : limit K to (bm+1)*128 (causal PV).
template<typename OUTT, bool BIAS, bool CSKIP, bool KLIM>
__global__ __launch_bounds__(256, 2)
void gemm_bt(const u16* __restrict__ Aall, const u16* __restrict__ Ball,
             const float* __restrict__ bias, OUTT* __restrict__ Call,
             int M, int N, int K, float scale, long sA, long sB, long sC) {
    const int bz = blockIdx.z;
    const u16* A = Aall + (long)bz * sA;
    const u16* Bm = Ball + (long)bz * sB;
    OUTT* C = Call + (long)bz * sC;
    const int bm = blockIdx.y, bn = blockIdx.x;
    if (CSKIP && bn > bm) return;
    int Keff = K;
    if (KLIM) { int kl = (bm + 1) * 128; Keff = kl < K ? kl : K; }

    __shared__ u16 As[128 * 32];
    __shared__ u16 Bs[128 * 32];

    const int tid = threadIdx.x;
    const int lane = tid & 63;
    const int w = tid >> 6;
    const int wr = (w >> 1) * 64;   // wave row offset within tile
    const int wc = (w & 1) * 64;    // wave col offset

    const int fr = lane & 15;
    const int fk = (lane >> 4) * 8;

    f32x4 acc[4][4] = {};

    const long rowA0 = (long)bm * 128;
    const long colB0 = (long)bn * 128;

    for (int k0 = 0; k0 < Keff; k0 += 32) {
        #pragma unroll
        for (int rr = 0; rr < 2; ++rr) {
            int c = rr * 256 + tid;                 // 16B chunk id, 512 per tile
            const u16* gA = A + (rowA0 + (c >> 2)) * K + k0 + (c & 3) * 8;
            async_copy16(gA, As + (rr * 256 + w * 64) * 8);
            const u16* gB = Bm + (colB0 + (c >> 2)) * K + k0 + (c & 3) * 8;
            async_copy16(gB, Bs + (rr * 256 + w * 64) * 8);
        }
        __syncthreads();

        bf16x8 af[4], bfv[4];
        #pragma unroll
        for (int m = 0; m < 4; ++m)
            af[m] = *(const bf16x8*)(As + (wr + m * 16 + fr) * 32 + fk);
        #pragma unroll
        for (int n = 0; n < 4; ++n)
            bfv[n] = *(const bf16x8*)(Bs + (wc + n * 16 + fr) * 32 + fk);
        #pragma unroll
        for (int m = 0; m < 4; ++m)
            #pragma unroll
            for (int n = 0; n < 4; ++n)
                acc[m][n] = __builtin_amdgcn_mfma_f32_16x16x32_bf16(af[m], bfv[n], acc[m][n], 0, 0, 0);
        __syncthreads();
    }

    // epilogue: C/D layout col=lane&15, row=(lane>>4)*4+j
    const int crow0 = (int)rowA0 + wr + (lane >> 4) * 4;
    const int ccol0 = (int)colB0 + wc + (lane & 15);
    #pragma unroll
    for (int m = 0; m < 4; ++m) {
        #pragma unroll
        for (int n = 0; n < 4; ++n) {
            int col = ccol0 + n * 16;
            float bvv = BIAS ? bias[col] : 0.f;
            #pragma unroll
            for (int j = 0; j < 4; ++j) {
                int rowi = crow0 + m * 16 + j;
                float v = acc[m][n][j] * scale + bvv;
                if constexpr (sizeof(OUTT) == 2) {
                    C[(long)rowi * N + col] = (OUTT)f2b(v);
                } else {
                    C[(long)rowi * N + col] = v;
                }
            }
        }
    }
}

extern "C" void kernel_launch(void* const* d_in, const int* in_sizes, int n_in,
                              void* d_out, int out_size, void* d_ws, size_t ws_size,
                              hipStream_t stream) {
    const float* x  = (const float*)d_in[0];
    // d_in[1] = mask (deterministic tril) - causal handled analytically
    const float* Wq = (const float*)d_in[2];
    const float* bq = (const float*)d_in[3];
    // d_in[4], d_in[5] = Wk, bk : dead code in reference
    const float* Wv = (const float*)d_in[6];
    const float* bv = (const float*)d_in[7];
    const float* Wo = (const float*)d_in[8];
    const float* bo = (const float*)d_in[9];
    float* out = (float*)d_out;

    const long B = 8, S = 2048, D = 1024;
    const long MS = B * S;                 // 16384

    char* p = (char*)d_ws;
    u16* xb  = (u16*)p; p += MS * D * 2;   // also reused as ctxb later
    u16* Wqb = (u16*)p; p += D * D * 2;
    u16* Wvb = (u16*)p; p += D * D * 2;
    u16* Wob = (u16*)p; p += D * D * 2;
    u16* Qb  = (u16*)p; p += MS * D * 2;   // reused as Vtb after scores
    u16* Vb  = (u16*)p; p += MS * D * 2;
    u16* Sb  = (u16*)p; p += B * S * S * 2;
    u16* ctxb = xb;                        // alias: x dead after projections
    u16* Vtb  = Qb;                        // alias: Q dead after scores

    // 1. casts
    cast_kernel<<<4096, 256, 0, stream>>>(x, xb, MS * D);
    cast_kernel<<<512, 256, 0, stream>>>(Wq, Wqb, D * D);
    cast_kernel<<<512, 256, 0, stream>>>(Wv, Wvb, D * D);
    cast_kernel<<<512, 256, 0, stream>>>(Wo, Wob, D * D);

    // 2. projections: Q = xb*Wq^T + bq ; V = xb*Wv^T + bv
    dim3 gproj(D / 128, MS / 128, 1);
    gemm_bt<u16, true, false, false><<<gproj, 256, 0, stream>>>(
        xb, Wqb, bq, Qb, (int)MS, (int)D, (int)D, 1.0f, 0, 0, 0);
    gemm_bt<u16, true, false, false><<<gproj, 256, 0, stream>>>(
        xb, Wvb, bv, Vb, (int)MS, (int)D, (int)D, 1.0f, 0, 0, 0);

    // 3. scores = Q*V^T / 32, lower-triangle blocks only
    dim3 gsc(S / 128, S / 128, B);
    gemm_bt<u16, false, true, false><<<gsc, 256, 0, stream>>>(
        Qb, Vb, nullptr, Sb, (int)S, (int)S, (int)D, 0.03125f, S * D, S * D, S * S);

    // 4. softmax rows (causal prefix), zero-pad to 128-aligned K-limit
    softmax_kernel<<<MS, 256, 0, stream>>>(Sb);

    // 5. V^T for PV GEMM fragment layout (aliases Qb; Q dead now)
    dim3 gtr(D / 32, S / 32, B);
    transpose_kernel<<<gtr, dim3(32, 8), 0, stream>>>(Vb, Vtb, (int)S, (int)D);

    // 6. ctx = P * V  (K limited per row-block by causality)
    dim3 gpv(D / 128, S / 128, B);
    gemm_bt<u16, false, false, true><<<gpv, 256, 0, stream>>>(
        Sb, Vtb, nullptr, ctxb, (int)S, (int)D, (int)S, 1.0f, S * S, D * S, S * D);

    // 7. out = ctx*Wo^T + bo (fp32 out)
    gemm_bt<float, true, false, false><<<gproj, 256, 0, stream>>>(
        ctxb, Wob, bo, out, (int)MS, (int)D, (int)D, 1.0f, 0, 0, 0);
}

// Round 2
// 558.981 us; speedup vs baseline: 1.0875x; 1.0875x over previous
//
#include <hip/hip_runtime.h>

typedef unsigned short u16;
typedef __attribute__((ext_vector_type(8))) unsigned short u16x8;
typedef __bf16 bf16x8 __attribute__((ext_vector_type(8)));
typedef float f32x4 __attribute__((ext_vector_type(4)));

__device__ __forceinline__ u16 f2b(float f) {
    unsigned u = __float_as_uint(f);
    u += 0x7fffu + ((u >> 16) & 1u);   // RNE bf16 (finite values only)
    return (u16)(u >> 16);
}
__device__ __forceinline__ float b2f(u16 h) {
    return __uint_as_float(((unsigned)h) << 16);
}

__device__ __forceinline__ void async_copy16(const void* g, void* l) {
    __builtin_amdgcn_global_load_lds(
        (const __attribute__((address_space(1))) unsigned int*)g,
        (__attribute__((address_space(3))) unsigned int*)l,
        16, 0, 0);
}

// st_16x32 swizzle (involution): byte ^= ((byte>>9)&1)<<5
__device__ __forceinline__ int swz(int x) { return x ^ (((x >> 9) & 1) << 5); }

// ---------------- cast f32 -> bf16, 8 elems/thread ----------------
__global__ __launch_bounds__(256) void cast_kernel(const float* __restrict__ in,
                                                   u16* __restrict__ out, long n) {
    long i0 = ((long)blockIdx.x * 256 + threadIdx.x) * 8;
    long stride = (long)gridDim.x * 256 * 8;
    for (long i = i0; i < n; i += stride) {
        float4 a = *(const float4*)(in + i);
        float4 b = *(const float4*)(in + i + 4);
        u16x8 o;
        o[0] = f2b(a.x); o[1] = f2b(a.y); o[2] = f2b(a.z); o[3] = f2b(a.w);
        o[4] = f2b(b.x); o[5] = f2b(b.y); o[6] = f2b(b.z); o[7] = f2b(b.w);
        *(u16x8*)(out + i) = o;
    }
}

// ---------------- bf16 transpose (per batch) ----------------
__global__ __launch_bounds__(256) void transpose_kernel(const u16* __restrict__ in,
                                                        u16* __restrict__ out,
                                                        int rows, int cols) {
    __shared__ u16 tile[32][33];
    long base = (long)blockIdx.z * rows * cols;
    const u16* I = in + base;
    u16* O = out + base;
    int r0 = blockIdx.y * 32, c0 = blockIdx.x * 32;
    int tx = threadIdx.x, ty = threadIdx.y;
    #pragma unroll
    for (int j = ty; j < 32; j += 8)
        tile[j][tx] = I[(long)(r0 + j) * cols + c0 + tx];
    __syncthreads();
    #pragma unroll
    for (int j = ty; j < 32; j += 8)
        O[(long)(c0 + j) * rows + r0 + tx] = tile[tx][j];
}

// ---------------- row softmax over causal prefix, in place ----------------
// Row q valid cols [0,q]; writes softmax there, zeros up to roundup256(q+1)
// (PV K-tiles are 256-aligned now).
__global__ __launch_bounds__(256) void softmax_kernel(u16* __restrict__ Sc) {
    const int SS = 2048;
    long row = blockIdx.x;
    int q = (int)(row & (SS - 1));
    int L = q + 1;
    int Klim = ((q >> 8) + 1) << 8;       // roundup(L,256)
    u16* p = Sc + row * SS;
    int tid = threadIdx.x;

    float m = -1e30f;
    for (int i = tid; i < L; i += 256) m = fmaxf(m, b2f(p[i]));
    #pragma unroll
    for (int o = 32; o > 0; o >>= 1) m = fmaxf(m, __shfl_xor(m, o));
    __shared__ float redm[4];
    if ((tid & 63) == 0) redm[tid >> 6] = m;
    __syncthreads();
    m = fmaxf(fmaxf(redm[0], redm[1]), fmaxf(redm[2], redm[3]));

    float s = 0.f;
    for (int i = tid; i < L; i += 256) s += __expf(b2f(p[i]) - m);
    #pragma unroll
    for (int o = 32; o > 0; o >>= 1) s += __shfl_xor(s, o);
    __shared__ float reds[4];
    if ((tid & 63) == 0) reds[tid >> 6] = s;
    __syncthreads();
    s = reds[0] + reds[1] + reds[2] + reds[3];
    float inv = 1.f / s;

    for (int i = tid; i < Klim; i += 256) {
        float v = (i < L) ? __expf(b2f(p[i]) - m) * inv : 0.f;
        p[i] = f2b(v);
    }
}

// ---------------- 256x256 8-phase bf16 BT-GEMM (m201 structure) ----------------
// C[m,n] = (sum_k A[m,k]*B[n,k])*scale (+bias[n]); A:[M,K] B:[N,K] row-major.
// 512 threads = 8 waves (2M x 4N). BK=64. LDS 128KB: 2 bufs x 4 regions
// (A0,A1,B0,B1) x 16KB, st_16x32 swizzled. Wave(wm,wn) owns output rows
// {wm*64..+63, 128+wm*64..+63} x cols {wn*32..+31, 128+wn*32..+31}.
// Per K-tile 4 phases: ph1 reads A0+B0 (12 ds), ph2 B1 (4), ph3 A1 (8), ph4 none.
// Stage sequence runs 3 half-tiles ahead; vmcnt(6) only at ph4.
template<typename OUTT, bool BIAS, bool CSKIP, bool KLIM>
__global__ __launch_bounds__(512)
void gemm256(const u16* __restrict__ Aall, const u16* __restrict__ Ball,
             const float* __restrict__ bias, OUTT* __restrict__ Call,
             int M, int N, int K, float scale, long sA, long sB, long sC) {
    const int bz = blockIdx.z;
    const u16* A = Aall + (long)bz * sA;
    const u16* B = Ball + (long)bz * sB;
    OUTT* C = Call + (long)bz * sC;
    const int bm = blockIdx.y, bn = blockIdx.x;
    if (CSKIP && bn > bm) return;
    int Keff = K;
    if (KLIM) { int kl = (bm + 1) * 256; Keff = kl < K ? kl : K; }
    const int NT = Keff >> 6;            // K-tiles of 64

    extern __shared__ __align__(16) char lds[];

    const int tid = threadIdx.x;
    const int lane = tid & 63;
    const int w = tid >> 6;
    const int wm = w >> 2, wn = w & 3;
    const int fr = lane & 15, hi = lane >> 4;
    const int axor = ((fr >> 2) & 1) << 5;   // swz bit for frag reads

    const long rowA0 = (long)bm * 256;
    const long rowB0 = (long)bn * 256;

    // stage one 128x64 half-tile (16KB): linear LDS dest, pre-swizzled source
    auto stage_half = [&](const u16* mat, long gr0, int k0, char* region) {
        #pragma unroll
        for (int rd = 0; rd < 2; ++rd) {
            int pb = rd * 8192 + w * 1024;     // wave-uniform base
            int p = pb + lane * 16;            // lane's physical byte
            int L = swz(p);                    // logical byte
            const u16* src = mat + (gr0 + (L >> 7)) * (long)K + k0 + ((L & 127) >> 1);
            async_copy16(src, region + pb);
        }
    };

    f32x4 acc[8][4] = {};
    bf16x8 a[4][2], b0[2][2], b1[2][2];

    char* bufp0 = lds;
    char* bufp1 = lds + 65536;

    // ---- prologue: tile0 {A0,B0,B1,A1}, vmcnt(4), tile1 {A0,B0,B1}, vmcnt(6)
    stage_half(A, rowA0,       0, bufp0 + 0 * 16384);
    stage_half(B, rowB0,       0, bufp0 + 2 * 16384);
    stage_half(B, rowB0 + 128, 0, bufp0 + 3 * 16384);
    stage_half(A, rowA0 + 128, 0, bufp0 + 1 * 16384);
    asm volatile("s_waitcnt vmcnt(4)" ::: "memory");
    if (1 < NT) {
        stage_half(A, rowA0,       64, bufp1 + 0 * 16384);
        stage_half(B, rowB0,       64, bufp1 + 2 * 16384);
        stage_half(B, rowB0 + 128, 64, bufp1 + 3 * 16384);
    }
    asm volatile("s_waitcnt vmcnt(6)" ::: "memory");
    __builtin_amdgcn_s_barrier();

    const int abase = (wm * 64 + fr) * 128 + hi * 16;   // A logical byte base
    const int bbase = (wn * 32 + fr) * 128 + hi * 16;   // B logical byte base

    for (int u = 0; u < NT; ++u) {
        char* bufp  = (u & 1) ? bufp1 : bufp0;
        char* obufp = (u & 1) ? bufp0 : bufp1;

        // ===== phase 1: read A-low + B-low; stage A1(u+1) =====
        #pragma unroll
        for (int m = 0; m < 4; ++m)
            #pragma unroll
            for (int kk = 0; kk < 2; ++kk)
                a[m][kk] = *(const bf16x8*)(bufp + 0 * 16384 + ((abase + m * 2048 + kk * 64) ^ axor));
        #pragma unroll
        for (int nl = 0; nl < 2; ++nl)
            #pragma unroll
            for (int kk = 0; kk < 2; ++kk)
                b0[nl][kk] = *(const bf16x8*)(bufp + 2 * 16384 + ((bbase + nl * 2048 + kk * 64) ^ axor));
        if (u + 1 < NT)
            stage_half(A, rowA0 + 128, (u + 1) * 64, obufp + 1 * 16384);
        asm volatile("s_waitcnt lgkmcnt(8)" ::: "memory");
        __builtin_amdgcn_s_barrier();
        asm volatile("s_waitcnt lgkmcnt(0)" ::: "memory");
        __builtin_amdgcn_sched_barrier(0);
        __builtin_amdgcn_s_setprio(1);
        #pragma unroll
        for (int m = 0; m < 4; ++m)
            #pragma unroll
            for (int nl = 0; nl < 2; ++nl)
                #pragma unroll
                for (int kk = 0; kk < 2; ++kk)
                    acc[m][nl] = __builtin_amdgcn_mfma_f32_16x16x32_bf16(a[m][kk], b0[nl][kk], acc[m][nl], 0, 0, 0);
        __builtin_amdgcn_s_setprio(0);
        __builtin_amdgcn_s_barrier();

        // ===== phase 2: read B-high; stage A0(u+2) =====
        #pragma unroll
        for (int nl = 0; nl < 2; ++nl)
            #pragma unroll
            for (int kk = 0; kk < 2; ++kk)
                b1[nl][kk] = *(const bf16x8*)(bufp + 3 * 16384 + ((bbase + nl * 2048 + kk * 64) ^ axor));
        if (u + 2 < NT)
            stage_half(A, rowA0, (u + 2) * 64, bufp + 0 * 16384);
        __builtin_amdgcn_s_barrier();
        asm volatile("s_waitcnt lgkmcnt(0)" ::: "memory");
        __builtin_amdgcn_sched_barrier(0);
        __builtin_amdgcn_s_setprio(1);
        #pragma unroll
        for (int m = 0; m < 4; ++m)
            #pragma unroll
            for (int nl = 0; nl < 2; ++nl)
                #pragma unroll
                for (int kk = 0; kk < 2; ++kk)
                    acc[m][2 + nl] = __builtin_amdgcn_mfma_f32_16x16x32_bf16(a[m][kk], b1[nl][kk], acc[m][2 + nl], 0, 0, 0);
        __builtin_amdgcn_s_setprio(0);
        __builtin_amdgcn_s_barrier();

        // ===== phase 3: read A-high (reuse a regs); stage B0(u+2) =====
        #pragma unroll
        for (int m = 0; m < 4; ++m)
            #pragma unroll
            for (int kk = 0; kk < 2; ++kk)
                a[m][kk] = *(const bf16x8*)(bufp + 1 * 16384 + ((abase + m * 2048 + kk * 64) ^ axor));
        if (u + 2 < NT)
            stage_half(B, rowB0, (u + 2) * 64, bufp + 2 * 16384);
        __builtin_amdgcn_s_barrier();
        asm volatile("s_waitcnt lgkmcnt(0)" ::: "memory");
        __builtin_amdgcn_sched_barrier(0);
        __builtin_amdgcn_s_setprio(1);
        #pragma unroll
        for (int m = 0; m < 4; ++m)
            #pragma unroll
            for (int nl = 0; nl < 2; ++nl)
                #pragma unroll
                for (int kk = 0; kk < 2; ++kk)
                    acc[4 + m][2 + nl] = __builtin_amdgcn_mfma_f32_16x16x32_bf16(a[m][kk], b1[nl][kk], acc[4 + m][2 + nl], 0, 0, 0);
        __builtin_amdgcn_s_setprio(0);
        __builtin_amdgcn_s_barrier();

        // ===== phase 4: no reads; stage B1(u+2); counted vmcnt =====
        if (u + 2 < NT)
            stage_half(B, rowB0 + 128, (u + 2) * 64, bufp + 3 * 16384);
        __builtin_amdgcn_s_barrier();
        __builtin_amdgcn_s_setprio(1);
        #pragma unroll
        for (int m = 0; m < 4; ++m)
            #pragma unroll
            for (int nl = 0; nl < 2; ++nl)
                #pragma unroll
                for (int kk = 0; kk < 2; ++kk)
                    acc[4 + m][nl] = __builtin_amdgcn_mfma_f32_16x16x32_bf16(a[m][kk], b0[nl][kk], acc[4 + m][nl], 0, 0, 0);
        __builtin_amdgcn_s_setprio(0);
        if (u < NT - 2) { asm volatile("s_waitcnt vmcnt(6)" ::: "memory"); }
        else            { asm volatile("s_waitcnt vmcnt(0)" ::: "memory"); }
        __builtin_amdgcn_s_barrier();
    }

    // ---- epilogue ----
    #pragma unroll
    for (int m = 0; m < 8; ++m) {
        int rl = (m < 4) ? (wm * 64 + m * 16) : (128 + wm * 64 + (m - 4) * 16);
        long grow = rowA0 + rl + hi * 4;
        #pragma unroll
        for (int n = 0; n < 4; ++n) {
            int cl = (n < 2) ? (wn * 32 + n * 16) : (128 + wn * 32 + (n - 2) * 16);
            long gcol = rowB0 + cl + fr;
            float bvv = BIAS ? bias[gcol] : 0.f;
            #pragma unroll
            for (int j = 0; j < 4; ++j) {
                float v = acc[m][n][j] * scale + bvv;
                if constexpr (sizeof(OUTT) == 2) {
                    C[(grow + j) * N + gcol] = (OUTT)f2b(v);
                } else {
                    C[(grow + j) * N + gcol] = v;
                }
            }
        }
    }
}

extern "C" void kernel_launch(void* const* d_in, const int* in_sizes, int n_in,
                              void* d_out, int out_size, void* d_ws, size_t ws_size,
                              hipStream_t stream) {
    (void)in_sizes; (void)n_in; (void)out_size; (void)ws_size;
    const float* x  = (const float*)d_in[0];
    // d_in[1] = mask (deterministic tril) - handled analytically
    const float* Wq = (const float*)d_in[2];
    const float* bq = (const float*)d_in[3];
    // d_in[4], d_in[5] = Wk, bk : dead code in reference
    const float* Wv = (const float*)d_in[6];
    const float* bv = (const float*)d_in[7];
    const float* Wo = (const float*)d_in[8];
    const float* bo = (const float*)d_in[9];
    float* out = (float*)d_out;

    const long B = 8, S = 2048, D = 1024;
    const long MS = B * S;                 // 16384

    char* p = (char*)d_ws;
    u16* xb  = (u16*)p; p += MS * D * 2;   // reused as ctxb later
    u16* Wqb = (u16*)p; p += D * D * 2;
    u16* Wvb = (u16*)p; p += D * D * 2;
    u16* Wob = (u16*)p; p += D * D * 2;
    u16* Qb  = (u16*)p; p += MS * D * 2;   // reused as Vtb after scores
    u16* Vb  = (u16*)p; p += MS * D * 2;
    u16* Sb  = (u16*)p; p += B * S * S * 2;
    u16* ctxb = xb;
    u16* Vtb  = Qb;

    const int SMEM = 131072;
    (void)hipFuncSetAttribute((const void*)gemm256<u16, true, false, false>,
                              hipFuncAttributeMaxDynamicSharedMemorySize, SMEM);
    (void)hipFuncSetAttribute((const void*)gemm256<u16, false, true, false>,
                              hipFuncAttributeMaxDynamicSharedMemorySize, SMEM);
    (void)hipFuncSetAttribute((const void*)gemm256<u16, false, false, true>,
                              hipFuncAttributeMaxDynamicSharedMemorySize, SMEM);
    (void)hipFuncSetAttribute((const void*)gemm256<float, true, false, false>,
                              hipFuncAttributeMaxDynamicSharedMemorySize, SMEM);

    // 1. casts
    cast_kernel<<<4096, 256, 0, stream>>>(x, xb, MS * D);
    cast_kernel<<<512, 256, 0, stream>>>(Wq, Wqb, D * D);
    cast_kernel<<<512, 256, 0, stream>>>(Wv, Wvb, D * D);
    cast_kernel<<<512, 256, 0, stream>>>(Wo, Wob, D * D);

    // 2. projections
    dim3 gproj(D / 256, MS / 256, 1);
    gemm256<u16, true, false, false><<<gproj, 512, SMEM, stream>>>(
        xb, Wqb, bq, Qb, (int)MS, (int)D, (int)D, 1.0f, 0, 0, 0);
    gemm256<u16, true, false, false><<<gproj, 512, SMEM, stream>>>(
        xb, Wvb, bv, Vb, (int)MS, (int)D, (int)D, 1.0f, 0, 0, 0);

    // 3. scores = Q*V^T / 32, lower-triangle 256-blocks only
    dim3 gsc(S / 256, S / 256, B);
    gemm256<u16, false, true, false><<<gsc, 512, SMEM, stream>>>(
        Qb, Vb, nullptr, Sb, (int)S, (int)S, (int)D, 0.03125f, S * D, S * D, S * S);

    // 4. softmax rows (causal prefix), zero-pad to 256-aligned K-limit
    softmax_kernel<<<MS, 256, 0, stream>>>(Sb);

    // 5. V^T (aliases Qb; Q dead now)
    dim3 gtr(D / 32, S / 32, B);
    transpose_kernel<<<gtr, dim3(32, 8), 0, stream>>>(Vb, Vtb, (int)S, (int)D);

    // 6. ctx = P * V (K limited per row-block by causality)
    dim3 gpv(D / 256, S / 256, B);
    gemm256<u16, false, false, true><<<gpv, 512, SMEM, stream>>>(
        Sb, Vtb, nullptr, ctxb, (int)S, (int)D, (int)S, 1.0f, S * S, D * S, S * D);

    // 7. out = ctx*Wo^T + bo (fp32 out)
    gemm256<float, true, false, false><<<gproj, 512, SMEM, stream>>>(
        ctxb, Wob, bo, out, (int)MS, (int)D, (int)D, 1.0f, 0, 0, 0);
}

// Round 4
// 505.655 us; speedup vs baseline: 1.2022x; 1.1055x over previous
//
#include <hip/hip_runtime.h>

typedef unsigned short u16;
typedef __attribute__((ext_vector_type(8))) unsigned short u16x8;
typedef __bf16 bf16x8 __attribute__((ext_vector_type(8)));
typedef float f32x4 __attribute__((ext_vector_type(4)));

__device__ __forceinline__ u16 f2b(float f) {
    unsigned u = __float_as_uint(f);
    u += 0x7fffu + ((u >> 16) & 1u);   // RNE bf16 (finite values only)
    return (u16)(u >> 16);
}
__device__ __forceinline__ float b2f(u16 h) {
    return __uint_as_float(((unsigned)h) << 16);
}

__device__ __forceinline__ void async_copy16(const void* g, void* l) {
    __builtin_amdgcn_global_load_lds(
        (const __attribute__((address_space(1))) unsigned int*)g,
        (__attribute__((address_space(3))) unsigned int*)l,
        16, 0, 0);
}

// Bank-spread swizzle for [row][128B] tiles read as 16B chunks (G4 formula):
// byte ^= ((row&7)<<4). Involution (bits [6:4] keyed by bits [9:7]).
__device__ __forceinline__ int swz(int x) { return x ^ (((x >> 7) & 7) << 4); }

// ---------------- cast f32 -> bf16, 8 elems/thread ----------------
__global__ __launch_bounds__(256) void cast_kernel(const float* __restrict__ in,
                                                   u16* __restrict__ out, long n) {
    long i0 = ((long)blockIdx.x * 256 + threadIdx.x) * 8;
    long stride = (long)gridDim.x * 256 * 8;
    for (long i = i0; i < n; i += stride) {
        float4 a = *(const float4*)(in + i);
        float4 b = *(const float4*)(in + i + 4);
        u16x8 o;
        o[0] = f2b(a.x); o[1] = f2b(a.y); o[2] = f2b(a.z); o[3] = f2b(a.w);
        o[4] = f2b(b.x); o[5] = f2b(b.y); o[6] = f2b(b.z); o[7] = f2b(b.w);
        *(u16x8*)(out + i) = o;
    }
}

// ---------------- bf16 transpose, 64x64 tiles, vectorized both sides -------
// in: [S][D] per batch; out: [D][S]. LDS tile swizzled by ((row>>3)&7)<<4.
__global__ __launch_bounds__(256) void transpose_kernel(const u16* __restrict__ in,
                                                        u16* __restrict__ out,
                                                        int S_, int D_) {
    __shared__ u16 tile[64 * 64];
    long base = (long)blockIdx.z * (long)S_ * D_;
    int r0 = blockIdx.y * 64;   // s
    int c0 = blockIdx.x * 64;   // d
    int t = threadIdx.x;
    {
        int r = t >> 3, cb = (t & 7) * 16;   // byte col
        #pragma unroll
        for (int h = 0; h < 2; ++h) {
            int rr = r + h * 32;
            u16x8 d8 = *(const u16x8*)(in + base + (long)(r0 + rr) * D_ + c0 + (cb >> 1));
            int phys = rr * 128 + (cb ^ (((rr >> 3) & 7) << 4));
            *(u16x8*)((char*)tile + phys) = d8;
        }
    }
    __syncthreads();
    {
        int od = t & 63;
        int gb = (t >> 6) * 2;
        #pragma unroll
        for (int h = 0; h < 2; ++h) {
            int g = gb + h;
            u16x8 o8;
            #pragma unroll
            for (int j = 0; j < 8; ++j) {
                int rr = g * 8 + j;
                int phys = rr * 128 + ((od * 2) ^ (((rr >> 3) & 7) << 4));
                o8[j] = *(const u16*)((char*)tile + phys);
            }
            *(u16x8*)(out + base + (long)(c0 + od) * S_ + r0 + g * 8) = o8;
        }
    }
}

// ---------------- single-pass row softmax over causal prefix, in place -----
// Row q valid cols [0,q]; softmax there, zeros to roundup256(q+1). 256 thr x 8.
__global__ __launch_bounds__(256) void softmax_kernel(u16* __restrict__ Sc) {
    const int SS = 2048;
    long row = blockIdx.x;
    int q = (int)(row & (SS - 1));
    int L = q + 1;
    int Klim = ((q >> 8) + 1) << 8;       // roundup(L,256)
    u16* p = Sc + row * SS;
    int tid = threadIdx.x;
    int i0 = tid * 8;

    float v[8];
    if (i0 < Klim) {
        u16x8 raw = *(const u16x8*)(p + i0);
        #pragma unroll
        for (int j = 0; j < 8; ++j)
            v[j] = (i0 + j < L) ? b2f(raw[j]) : -1e30f;
    } else {
        #pragma unroll
        for (int j = 0; j < 8; ++j) v[j] = -1e30f;
    }

    float m = v[0];
    #pragma unroll
    for (int j = 1; j < 8; ++j) m = fmaxf(m, v[j]);
    #pragma unroll
    for (int o = 32; o > 0; o >>= 1) m = fmaxf(m, __shfl_xor(m, o));
    __shared__ float red[8];
    if ((tid & 63) == 0) red[tid >> 6] = m;
    __syncthreads();
    m = fmaxf(fmaxf(red[0], red[1]), fmaxf(red[2], red[3]));

    float e[8];
    float s = 0.f;
    #pragma unroll
    for (int j = 0; j < 8; ++j) { e[j] = __expf(v[j] - m); s += e[j]; }
    #pragma unroll
    for (int o = 32; o > 0; o >>= 1) s += __shfl_xor(s, o);
    if ((tid & 63) == 0) red[4 + (tid >> 6)] = s;
    __syncthreads();
    s = red[4] + red[5] + red[6] + red[7];
    float inv = 1.f / s;

    if (i0 < Klim) {
        u16x8 o8;
        #pragma unroll
        for (int j = 0; j < 8; ++j) o8[j] = f2b(e[j] * inv);
        *(u16x8*)(p + i0) = o8;
    }
}

// ---------------- 256x256 8-phase bf16 BT-GEMM ----------------
// C[m,n] = (sum_k A[m,k]*B[n,k])*scale (+bias[n]); A:[M,K] B:[N,K] row-major.
// 512 threads = 8 waves (2M x 4N). BK=64. LDS 128KB: 2 bufs x 4 regions
// (A0,A1,B0,B1) x 16KB, swizzle byte^=((row&7)<<4). Stage 3 half-tiles ahead;
// vmcnt(6) only at ph4. bz selects batch via sA/sB/sC; bias2 (if nonnull)
// used for bz==1 (fused QV projection).
template<typename OUTT, bool BIAS, bool CSKIP, bool KLIM>
__global__ __launch_bounds__(512)
void gemm256(const u16* __restrict__ Aall, const u16* __restrict__ Ball,
             const float* __restrict__ bias, const float* __restrict__ bias2,
             OUTT* __restrict__ Call,
             int M, int N, int K, float scale, long sA, long sB, long sC) {
    const int bz = blockIdx.z;
    const u16* A = Aall + (long)bz * sA;
    const u16* B = Ball + (long)bz * sB;
    OUTT* C = Call + (long)bz * sC;
    const float* bp = (bz && bias2) ? bias2 : bias;
    const int bm = blockIdx.y, bn = blockIdx.x;
    if (CSKIP && bn > bm) return;
    int Keff = K;
    if (KLIM) { int kl = (bm + 1) * 256; Keff = kl < K ? kl : K; }
    const int NT = Keff >> 6;            // K-tiles of 64

    extern __shared__ __align__(16) char lds[];

    const int tid = threadIdx.x;
    const int lane = tid & 63;
    const int w = tid >> 6;
    const int wm = w >> 2, wn = w & 3;
    const int fr = lane & 15, hi = lane >> 4;
    const int axor = (fr & 7) << 4;      // = ((row&7)<<4), row = ..16*m + fr

    const long rowA0 = (long)bm * 256;
    const long rowB0 = (long)bn * 256;

    // stage one 128x64 half-tile (16KB): linear LDS dest, inverse-swizzled src
    auto stage_half = [&](const u16* mat, long gr0, int k0, char* region) {
        #pragma unroll
        for (int rd = 0; rd < 2; ++rd) {
            int pb = rd * 8192 + w * 1024;     // wave-uniform base
            int p = pb + lane * 16;            // lane's physical byte
            int Lb = swz(p);                   // logical byte
            const u16* src = mat + (gr0 + (Lb >> 7)) * (long)K + k0 + ((Lb & 127) >> 1);
            async_copy16(src, region + pb);
        }
    };

    f32x4 acc[8][4] = {};
    bf16x8 a[4][2], b0[2][2], b1[2][2];

    char* bufp0 = lds;
    char* bufp1 = lds + 65536;

    // ---- prologue
    stage_half(A, rowA0,       0, bufp0 + 0 * 16384);
    stage_half(B, rowB0,       0, bufp0 + 2 * 16384);
    stage_half(B, rowB0 + 128, 0, bufp0 + 3 * 16384);
    stage_half(A, rowA0 + 128, 0, bufp0 + 1 * 16384);
    asm volatile("s_waitcnt vmcnt(4)" ::: "memory");
    if (1 < NT) {
        stage_half(A, rowA0,       64, bufp1 + 0 * 16384);
        stage_half(B, rowB0,       64, bufp1 + 2 * 16384);
        stage_half(B, rowB0 + 128, 64, bufp1 + 3 * 16384);
    }
    asm volatile("s_waitcnt vmcnt(6)" ::: "memory");
    __builtin_amdgcn_s_barrier();

    const int abase = (wm * 64 + fr) * 128 + hi * 16;   // A logical byte base
    const int bbase = (wn * 32 + fr) * 128 + hi * 16;   // B logical byte base

    for (int u = 0; u < NT; ++u) {
        char* bufp  = (u & 1) ? bufp1 : bufp0;
        char* obufp = (u & 1) ? bufp0 : bufp1;

        // ===== phase 1: read A-low + B-low; stage A1(u+1) =====
        #pragma unroll
        for (int m = 0; m < 4; ++m)
            #pragma unroll
            for (int kk = 0; kk < 2; ++kk)
                a[m][kk] = *(const bf16x8*)(bufp + 0 * 16384 + ((abase + m * 2048 + kk * 64) ^ axor));
        #pragma unroll
        for (int nl = 0; nl < 2; ++nl)
            #pragma unroll
            for (int kk = 0; kk < 2; ++kk)
                b0[nl][kk] = *(const bf16x8*)(bufp + 2 * 16384 + ((bbase + nl * 2048 + kk * 64) ^ axor));
        if (u + 1 < NT)
            stage_half(A, rowA0 + 128, (u + 1) * 64, obufp + 1 * 16384);
        asm volatile("s_waitcnt lgkmcnt(8)" ::: "memory");
        __builtin_amdgcn_s_barrier();
        asm volatile("s_waitcnt lgkmcnt(0)" ::: "memory");
        __builtin_amdgcn_sched_barrier(0);
        __builtin_amdgcn_s_setprio(1);
        #pragma unroll
        for (int m = 0; m < 4; ++m)
            #pragma unroll
            for (int nl = 0; nl < 2; ++nl)
                #pragma unroll
                for (int kk = 0; kk < 2; ++kk)
                    acc[m][nl] = __builtin_amdgcn_mfma_f32_16x16x32_bf16(a[m][kk], b0[nl][kk], acc[m][nl], 0, 0, 0);
        __builtin_amdgcn_s_setprio(0);
        __builtin_amdgcn_s_barrier();

        // ===== phase 2: read B-high; stage A0(u+2) =====
        #pragma unroll
        for (int nl = 0; nl < 2; ++nl)
            #pragma unroll
            for (int kk = 0; kk < 2; ++kk)
                b1[nl][kk] = *(const bf16x8*)(bufp + 3 * 16384 + ((bbase + nl * 2048 + kk * 64) ^ axor));
        if (u + 2 < NT)
            stage_half(A, rowA0, (u + 2) * 64, bufp + 0 * 16384);
        __builtin_amdgcn_s_barrier();
        asm volatile("s_waitcnt lgkmcnt(0)" ::: "memory");
        __builtin_amdgcn_sched_barrier(0);
        __builtin_amdgcn_s_setprio(1);
        #pragma unroll
        for (int m = 0; m < 4; ++m)
            #pragma unroll
            for (int nl = 0; nl < 2; ++nl)
                #pragma unroll
                for (int kk = 0; kk < 2; ++kk)
                    acc[m][2 + nl] = __builtin_amdgcn_mfma_f32_16x16x32_bf16(a[m][kk], b1[nl][kk], acc[m][2 + nl], 0, 0, 0);
        __builtin_amdgcn_s_setprio(0);
        __builtin_amdgcn_s_barrier();

        // ===== phase 3: read A-high (reuse a regs); stage B0(u+2) =====
        #pragma unroll
        for (int m = 0; m < 4; ++m)
            #pragma unroll
            for (int kk = 0; kk < 2; ++kk)
                a[m][kk] = *(const bf16x8*)(bufp + 1 * 16384 + ((abase + m * 2048 + kk * 64) ^ axor));
        if (u + 2 < NT)
            stage_half(B, rowB0, (u + 2) * 64, bufp + 2 * 16384);
        __builtin_amdgcn_s_barrier();
        asm volatile("s_waitcnt lgkmcnt(0)" ::: "memory");
        __builtin_amdgcn_sched_barrier(0);
        __builtin_amdgcn_s_setprio(1);
        #pragma unroll
        for (int m = 0; m < 4; ++m)
            #pragma unroll
            for (int nl = 0; nl < 2; ++nl)
                #pragma unroll
                for (int kk = 0; kk < 2; ++kk)
                    acc[4 + m][2 + nl] = __builtin_amdgcn_mfma_f32_16x16x32_bf16(a[m][kk], b1[nl][kk], acc[4 + m][2 + nl], 0, 0, 0);
        __builtin_amdgcn_s_setprio(0);
        __builtin_amdgcn_s_barrier();

        // ===== phase 4: no reads; stage B1(u+2); counted vmcnt =====
        if (u + 2 < NT)
            stage_half(B, rowB0 + 128, (u + 2) * 64, bufp + 3 * 16384);
        __builtin_amdgcn_s_barrier();
        __builtin_amdgcn_s_setprio(1);
        #pragma unroll
        for (int m = 0; m < 4; ++m)
            #pragma unroll
            for (int nl = 0; nl < 2; ++nl)
                #pragma unroll
                for (int kk = 0; kk < 2; ++kk)
                    acc[4 + m][nl] = __builtin_amdgcn_mfma_f32_16x16x32_bf16(a[m][kk], b0[nl][kk], acc[4 + m][nl], 0, 0, 0);
        __builtin_amdgcn_s_setprio(0);
        if (u < NT - 2) { asm volatile("s_waitcnt vmcnt(6)" ::: "memory"); }
        else            { asm volatile("s_waitcnt vmcnt(0)" ::: "memory"); }
        __builtin_amdgcn_s_barrier();
    }

    // ---- epilogue ----
    #pragma unroll
    for (int m = 0; m < 8; ++m) {
        int rl = (m < 4) ? (wm * 64 + m * 16) : (128 + wm * 64 + (m - 4) * 16);
        long grow = rowA0 + rl + hi * 4;
        #pragma unroll
        for (int n = 0; n < 4; ++n) {
            int cl = (n < 2) ? (wn * 32 + n * 16) : (128 + wn * 32 + (n - 2) * 16);
            long gcol = rowB0 + cl + fr;
            float bvv = BIAS ? bp[gcol] : 0.f;
            #pragma unroll
            for (int j = 0; j < 4; ++j) {
                float v = acc[m][n][j] * scale + bvv;
                if constexpr (sizeof(OUTT) == 2) {
                    C[(grow + j) * N + gcol] = (OUTT)f2b(v);
                } else {
                    C[(grow + j) * N + gcol] = v;
                }
            }
        }
    }
}

extern "C" void kernel_launch(void* const* d_in, const int* in_sizes, int n_in,
                              void* d_out, int out_size, void* d_ws, size_t ws_size,
                              hipStream_t stream) {
    (void)in_sizes; (void)n_in; (void)out_size; (void)ws_size;
    const float* x  = (const float*)d_in[0];
    // d_in[1] = mask (deterministic tril) - handled analytically
    const float* Wq = (const float*)d_in[2];
    const float* bq = (const float*)d_in[3];
    // d_in[4], d_in[5] = Wk, bk : dead code in reference
    const float* Wv = (const float*)d_in[6];
    const float* bv = (const float*)d_in[7];
    const float* Wo = (const float*)d_in[8];
    const float* bo = (const float*)d_in[9];
    float* out = (float*)d_out;

    const long B = 8, S = 2048, D = 1024;
    const long MS = B * S;                 // 16384

    char* p = (char*)d_ws;
    u16* xb  = (u16*)p; p += MS * D * 2;   // reused as ctxb later
    u16* Wqb = (u16*)p; p += D * D * 2;    // Wqb/Wvb adjacent (sB = D*D)
    u16* Wvb = (u16*)p; p += D * D * 2;
    u16* Wob = (u16*)p; p += D * D * 2;
    u16* Qb  = (u16*)p; p += MS * D * 2;   // Qb/Vb adjacent (sC = MS*D)
    u16* Vb  = (u16*)p; p += MS * D * 2;
    u16* Sb  = (u16*)p; p += B * S * S * 2;
    u16* ctxb = xb;
    u16* Vtb  = Qb;

    const int SMEM = 131072;
    (void)hipFuncSetAttribute((const void*)gemm256<u16, true, false, false>,
                              hipFuncAttributeMaxDynamicSharedMemorySize, SMEM);
    (void)hipFuncSetAttribute((const void*)gemm256<u16, false, true, false>,
                              hipFuncAttributeMaxDynamicSharedMemorySize, SMEM);
    (void)hipFuncSetAttribute((const void*)gemm256<u16, false, false, true>,
                              hipFuncAttributeMaxDynamicSharedMemorySize, SMEM);
    (void)hipFuncSetAttribute((const void*)gemm256<float, true, false, false>,
                              hipFuncAttributeMaxDynamicSharedMemorySize, SMEM);

    // 1. casts
    cast_kernel<<<4096, 256, 0, stream>>>(x, xb, MS * D);
    cast_kernel<<<512, 256, 0, stream>>>(Wq, Wqb, D * D);
    cast_kernel<<<512, 256, 0, stream>>>(Wv, Wvb, D * D);
    cast_kernel<<<512, 256, 0, stream>>>(Wo, Wob, D * D);

    // 2. fused Q+V projections (z=0: Q, z=1: V) — 512 blocks, 2 full rounds
    dim3 gqv(D / 256, MS / 256, 2);
    gemm256<u16, true, false, false><<<gqv, 512, SMEM, stream>>>(
        xb, Wqb, bq, bv, Qb, (int)MS, (int)D, (int)D, 1.0f, 0, D * D, MS * D);

    // 3. scores = Q*V^T / 32, lower-triangle 256-blocks only
    dim3 gsc(S / 256, S / 256, B);
    gemm256<u16, false, true, false><<<gsc, 512, SMEM, stream>>>(
        Qb, Vb, nullptr, nullptr, Sb, (int)S, (int)S, (int)D, 0.03125f, S * D, S * D, S * S);

    // 4. single-pass softmax (causal prefix), zero-pad to 256-aligned K-limit
    softmax_kernel<<<MS, 256, 0, stream>>>(Sb);

    // 5. V^T (aliases Qb; Q dead now)
    dim3 gtr(D / 64, S / 64, B);
    transpose_kernel<<<gtr, 256, 0, stream>>>(Vb, Vtb, (int)S, (int)D);

    // 6. ctx = P * V (K limited per row-block by causality)
    dim3 gpv(D / 256, S / 256, B);
    gemm256<u16, false, false, true><<<gpv, 512, SMEM, stream>>>(
        Sb, Vtb, nullptr, nullptr, ctxb, (int)S, (int)D, (int)S, 1.0f, S * S, D * S, S * D);

    // 7. out = ctx*Wo^T + bo (fp32 out)
    dim3 gproj(D / 256, MS / 256, 1);
    gemm256<float, true, false, false><<<gproj, 512, SMEM, stream>>>(
        ctxb, Wob, bo, nullptr, out, (int)MS, (int)D, (int)D, 1.0f, 0, 0, 0);
}